// Round 1
// 13843.365 us; speedup vs baseline: 1.1942x; 1.1942x over previous
//
#include <hip/hip_runtime.h>
#include <hip/hip_bf16.h>

#define NN 50000
#define TT 48
#define FIN 11
#define KAUG 288   // 256 (H) + 11 (X) + 21 pad zeros
#define MB ((NN + 63) / 64)

typedef __bf16 bf16_t;
typedef __bf16 v8bf __attribute__((ext_vector_type(8)));
typedef float v4f __attribute__((ext_vector_type(4)));

__device__ __forceinline__ float sigm_(float x) {
  return __builtin_amdgcn_rcpf(1.0f + __expf(-x));
}
__device__ __forceinline__ float tanh_(float x) {
  return 1.0f - 2.0f * __builtin_amdgcn_rcpf(1.0f + __expf(2.0f * x));
}

// ---------------- weight packing (bf16, augmented K) ----------------
// Bzr[512][288]: rows 0..255 -> [Wh0 | Wx0 | 0], rows 256..511 -> [Wh1 | Wx1 | 0]
// Bh [256][288]: [Wh2 | Wx2 | 0]
// Bu [1024][256]: uWx gate0, uWx gate2, spWx gate0, spWx gate2
__global__ void pack_w(const float* __restrict__ bbWx, const float* __restrict__ bbWh,
                       const float* __restrict__ uWx, const float* __restrict__ spWx,
                       bf16_t* __restrict__ Bzr, bf16_t* __restrict__ Bh,
                       bf16_t* __restrict__ Bu) {
  int i0 = blockIdx.x * blockDim.x + threadIdx.x;
  int stride = gridDim.x * blockDim.x;
  for (int idx = i0; idx < 512 * KAUG; idx += stride) {
    int n = idx / KAUG, k = idx - n * KAUG;
    int g = n >> 8, nn = n & 255;
    float v = 0.0f;
    if (k < 256) v = bbWh[(g * 256 + nn) * 256 + k];
    else if (k < 267) v = bbWx[(g * 256 + nn) * FIN + (k - 256)];
    Bzr[idx] = (bf16_t)v;
  }
  for (int idx = i0; idx < 256 * KAUG; idx += stride) {
    int n = idx / KAUG, k = idx - n * KAUG;
    float v = 0.0f;
    if (k < 256) v = bbWh[(512 + n) * 256 + k];
    else if (k < 267) v = bbWx[(512 + n) * FIN + (k - 256)];
    Bh[idx] = (bf16_t)v;
  }
  for (int idx = i0; idx < 1024 * 256; idx += stride) {
    int n = idx >> 8, k = idx & 255;
    int g = n >> 8, nn = n & 255;
    const float* W = (g < 2) ? uWx : spWx;
    int gate = (g & 1) ? 2 : 0;
    Bu[idx] = (bf16_t)W[(gate * 256 + nn) * 256 + k];
  }
}

// ---------------- fused persistent sequence kernel ----------------
// One block owns 64 rows for all 48 timesteps. H lives in LDS, weights
// stream from L2 straight into MFMA B-fragments (no LDS staging, no
// barriers inside K-loops). XOR swizzle keeps ds_read_b128 conflict-free.
__global__ __launch_bounds__(256, 2) void fused_seq(
    const float* __restrict__ X,
    const bf16_t* __restrict__ Bzr, const bf16_t* __restrict__ Bh,
    const bf16_t* __restrict__ Bu,
    const float* __restrict__ bbx, const float* __restrict__ bbh,
    const float* __restrict__ ubx, const float* __restrict__ ubh,
    const float* __restrict__ spbx, const float* __restrict__ spbh,
    const float* __restrict__ Wu, const float* __restrict__ buv,
    const float* __restrict__ Ws, const float* __restrict__ bsv,
    const float* __restrict__ Wp, const float* __restrict__ bpv,
    float* __restrict__ out) {
  __shared__ __align__(16) bf16_t Hm[64 * 256];  // H cols 0..255, swizzled
  __shared__ __align__(16) bf16_t Ha[64 * 32];   // H aug cols 256..287 (X|pad)
  __shared__ __align__(16) bf16_t Rm[64 * 256];  // r*H  (reused as hs tile)
  __shared__ __align__(16) bf16_t Ra[64 * 32];   // aug copy for h-gemm
  char* const Hmb = (char*)Hm;
  char* const Hab = (char*)Ha;
  char* const Rmb = (char*)Rm;
  char* const Rab = (char*)Ra;

  const int tid = threadIdx.x;
  const int lane15 = tid & 15, quad = (tid & 63) >> 4, wave = tid >> 6;
  const int rowBase = blockIdx.x * 64;

  const int srow = tid >> 2, sj = tid & 3;  // X staging mapping
  const int sm = rowBase + srow;

  // ---- init: H = 0, aug = [X_0 | 0] ----
  {
    uint4 z4 = make_uint4(0u, 0u, 0u, 0u);
    for (int i = tid; i < 2048; i += 256) ((uint4*)Hmb)[i] = z4;
    ((uint4*)Hab)[tid] = z4;
  }
  __syncthreads();
  if (sm < NN) {
    bf16_t* xr = (bf16_t*)(Hab + (srow << 6));
    const float* xp = X + (long)sm * FIN;
    xr[sj] = (bf16_t)xp[sj];
    if (sj + 4 < FIN) xr[sj + 4] = (bf16_t)xp[sj + 4];
    if (sj + 8 < FIN) xr[sj + 8] = (bf16_t)xp[sj + 8];
  }
  __syncthreads();

  for (int t = 0; t < TT; ++t) {
    // ================= phase 1: z,r gemms (K=288) =================
    v4f az[4][4] = {}, ar[4][4] = {};
#pragma unroll
    for (int kt = 0; kt < 9; ++kt) {
      v8bf a[4];
#pragma unroll
      for (int mf = 0; mf < 4; ++mf) {
        const int row = mf * 16 + lane15;
        a[mf] = (kt < 8)
            ? *(const v8bf*)(Hmb + (row << 9) + ((kt * 64 + quad * 16) ^ ((row & 7) << 4)))
            : *(const v8bf*)(Hab + (row << 6) + quad * 16);
      }
      const int kb = kt * 32 + quad * 8;
      v8bf bz[4], br[4];
#pragma unroll
      for (int nf = 0; nf < 4; ++nf) {
        const int c = wave * 64 + nf * 16 + lane15;
        bz[nf] = *(const v8bf*)(Bzr + (long)c * KAUG + kb);
        br[nf] = *(const v8bf*)(Bzr + (long)(256 + c) * KAUG + kb);
      }
#pragma unroll
      for (int mf = 0; mf < 4; ++mf)
#pragma unroll
        for (int nf = 0; nf < 4; ++nf) {
          az[mf][nf] = __builtin_amdgcn_mfma_f32_16x16x32_bf16(a[mf], bz[nf], az[mf][nf], 0, 0, 0);
          ar[mf][nf] = __builtin_amdgcn_mfma_f32_16x16x32_bf16(a[mf], br[nf], ar[mf][nf], 0, 0, 0);
        }
    }
    v4f zreg[4][4];  // z stays in registers until the blend
#pragma unroll
    for (int nf = 0; nf < 4; ++nf) {
      const int c = wave * 64 + nf * 16 + lane15;
      const float bz_ = bbx[c] + bbh[c];
      const float br_ = bbx[256 + c] + bbh[256 + c];
#pragma unroll
      for (int mf = 0; mf < 4; ++mf)
#pragma unroll
        for (int rg = 0; rg < 4; ++rg) {
          const int m = mf * 16 + quad * 4 + rg;
          zreg[mf][nf][rg] = sigm_(az[mf][nf][rg] + bz_);
          const int off = ((c * 2) ^ ((m & 7) << 4)) + (m << 9);
          const float hp = (float)*(const bf16_t*)(Hmb + off);
          const float sg = sigm_(ar[mf][nf][rg] + br_);
          *(bf16_t*)(Rmb + off) = (bf16_t)(sg * hp);
        }
    }
    // copy aug cols (X_t | pad) into the rH tile for the h-gemm
    *(uint4*)(Rab + (srow << 6) + sj * 16) = *(const uint4*)(Hab + (srow << 6) + sj * 16);
    __syncthreads();

    // ================= phase 2: h_tilde gemm + blend + X_{t+1} =================
    float xv0 = 0.f, xv1 = 0.f, xv2 = 0.f;  // prefetch next X (hides under K-loop)
    if (t + 1 < TT && sm < NN) {
      const float* xp = X + ((long)(t + 1) * NN + sm) * FIN;
      xv0 = xp[sj];
      if (sj + 4 < FIN) xv1 = xp[sj + 4];
      if (sj + 8 < FIN) xv2 = xp[sj + 8];
    }
    v4f ah[4][4] = {};
#pragma unroll
    for (int kt = 0; kt < 9; ++kt) {
      v8bf a[4];
#pragma unroll
      for (int mf = 0; mf < 4; ++mf) {
        const int row = mf * 16 + lane15;
        a[mf] = (kt < 8)
            ? *(const v8bf*)(Rmb + (row << 9) + ((kt * 64 + quad * 16) ^ ((row & 7) << 4)))
            : *(const v8bf*)(Rab + (row << 6) + quad * 16);
      }
      const int kb = kt * 32 + quad * 8;
      v8bf bh[4];
#pragma unroll
      for (int nf = 0; nf < 4; ++nf) {
        const int c = wave * 64 + nf * 16 + lane15;
        bh[nf] = *(const v8bf*)(Bh + (long)c * KAUG + kb);
      }
#pragma unroll
      for (int mf = 0; mf < 4; ++mf)
#pragma unroll
        for (int nf = 0; nf < 4; ++nf)
          ah[mf][nf] = __builtin_amdgcn_mfma_f32_16x16x32_bf16(a[mf], bh[nf], ah[mf][nf], 0, 0, 0);
    }
#pragma unroll
    for (int nf = 0; nf < 4; ++nf) {
      const int c = wave * 64 + nf * 16 + lane15;
      const float bh_ = bbx[512 + c] + bbh[512 + c];
#pragma unroll
      for (int mf = 0; mf < 4; ++mf)
#pragma unroll
        for (int rg = 0; rg < 4; ++rg) {
          const int m = mf * 16 + quad * 4 + rg;
          char* hp_p = Hmb + (m << 9) + ((c * 2) ^ ((m & 7) << 4));
          const float htl = tanh_(ah[mf][nf][rg] + bh_);
          const float z = zreg[mf][nf][rg];
          const float hp = (float)*(const bf16_t*)hp_p;
          *(bf16_t*)hp_p = (bf16_t)(z * hp + (1.0f - z) * htl);
        }
    }
    {  // stage X_{t+1} into aug cols (zeros when past end / tail rows)
      bf16_t* xr = (bf16_t*)(Hab + (srow << 6));
      xr[sj] = (bf16_t)xv0;
      if (sj + 4 < FIN) xr[sj + 4] = (bf16_t)xv1;
      if (sj + 8 < FIN) xr[sj + 8] = (bf16_t)xv2;
    }
    __syncthreads();

    // ================= phase 3: gru_u / gru_sp (H=None) + heads =================
    for (int half = 0; half < 2; ++half) {
      const bf16_t* Bub = Bu + (long)half * 512 * 256;
      const float* gbx = half ? spbx : ubx;
      const float* gbh = half ? spbh : ubh;
      v4f au[4][8] = {};
#pragma unroll
      for (int kt = 0; kt < 8; ++kt) {
        v8bf a[4];
#pragma unroll
        for (int mf = 0; mf < 4; ++mf) {
          const int row = mf * 16 + lane15;
          a[mf] = *(const v8bf*)(Hmb + (row << 9) + ((kt * 64 + quad * 16) ^ ((row & 7) << 4)));
        }
        const int kb = kt * 32 + quad * 8;
        v8bf b[8];
#pragma unroll
        for (int nf = 0; nf < 8; ++nf) {
          const int rrow = ((nf & 4) ? 256 : 0) + wave * 64 + (nf & 3) * 16 + lane15;
          b[nf] = *(const v8bf*)(Bub + (long)rrow * 256 + kb);
        }
#pragma unroll
        for (int mf = 0; mf < 4; ++mf)
#pragma unroll
          for (int nf = 0; nf < 8; ++nf)
            au[mf][nf] = __builtin_amdgcn_mfma_f32_16x16x32_bf16(a[mf], b[nf], au[mf][nf], 0, 0, 0);
      }
#pragma unroll
      for (int nf = 0; nf < 4; ++nf) {
        const int j = wave * 64 + nf * 16 + lane15;
        const float b0 = gbx[j] + gbh[j];
        const float b1 = gbx[512 + j] + gbh[512 + j];
#pragma unroll
        for (int mf = 0; mf < 4; ++mf)
#pragma unroll
          for (int rg = 0; rg < 4; ++rg) {
            const int r = mf * 16 + quad * 4 + rg;
            const float zz = sigm_(au[mf][nf][rg] + b0);
            const float ht = tanh_(au[mf][nf + 4][rg] + b1);
            *(bf16_t*)(Rmb + (r << 9) + ((j * 2) ^ ((r & 7) << 4))) = (bf16_t)((1.0f - zz) * ht);
          }
      }
      __syncthreads();
      if (half == 0) {
        if (tid < 192) {
          const int r = tid / 3, k = tid - r * 3;
          const int m = rowBase + r;
          if (m < NN) {
            float s = 0.f;
            for (int j = 0; j < 256; j += 8) {
              v8bf hv = *(const v8bf*)(Rmb + (r << 9) + ((j * 2) ^ ((r & 7) << 4)));
              const float* w = Wu + k * 256 + j;
#pragma unroll
              for (int jj = 0; jj < 8; ++jj) s += (float)hv[jj] * w[jj];
            }
            out[(long)t * (NN * 3) + (long)m * 3 + k] = s + buv[k];
          }
        }
      } else {
        if (tid < 128) {
          const int r = tid >> 1, which = tid & 1;
          const int m = rowBase + r;
          if (m < NN) {
            const float* W = which ? Wp : Ws;
            float s = 0.f;
            for (int j = 0; j < 256; j += 8) {
              v8bf hv = *(const v8bf*)(Rmb + (r << 9) + ((j * 2) ^ ((r & 7) << 4)));
#pragma unroll
              for (int jj = 0; jj < 8; ++jj) s += (float)hv[jj] * W[j + jj];
            }
            s += which ? bpv[0] : bsv[0];
            out[(long)TT * NN * 3 + (long)which * TT * NN + (long)t * NN + m] = s;
          }
        }
      }
      __syncthreads();
    }
  }
}

extern "C" void kernel_launch(void* const* d_in, const int* in_sizes, int n_in,
                              void* d_out, int out_size, void* d_ws, size_t ws_size,
                              hipStream_t stream) {
  const float* X    = (const float*)d_in[0];
  // d_in[1] edge_index: unused (ChebConv K=1 ignores edges)
  const float* bbWx = (const float*)d_in[2];
  const float* bbbx = (const float*)d_in[3];
  const float* bbWh = (const float*)d_in[4];
  const float* bbbh = (const float*)d_in[5];
  const float* uWx  = (const float*)d_in[6];
  const float* ubx  = (const float*)d_in[7];
  const float* ubh  = (const float*)d_in[9];   // u_Wh (d_in[8]) is dead: H=None
  const float* spWx = (const float*)d_in[10];
  const float* spbx = (const float*)d_in[11];
  const float* spbh = (const float*)d_in[13];  // sp_Wh (d_in[12]) dead
  const float* Wu   = (const float*)d_in[14];
  const float* buv  = (const float*)d_in[15];
  const float* Ws   = (const float*)d_in[16];
  const float* bsv  = (const float*)d_in[17];
  const float* Wp   = (const float*)d_in[18];
  const float* bpv  = (const float*)d_in[19];
  float* out = (float*)d_out;

  char* ws = (char*)d_ws;
  bf16_t* Bzr = (bf16_t*)(ws);                 // 512*288*2 = 294,912
  bf16_t* Bh  = (bf16_t*)(ws + 294912);        // 256*288*2 = 147,456
  bf16_t* Bu  = (bf16_t*)(ws + 442368);        // 1024*256*2 = 524,288
  if (ws_size < (size_t)966656) return;

  pack_w<<<dim3(192), dim3(256), 0, stream>>>(bbWx, bbWh, uWx, spWx, Bzr, Bh, Bu);
  fused_seq<<<dim3(MB), dim3(256), 0, stream>>>(X, Bzr, Bh, Bu, bbbx, bbbh,
                                                ubx, ubh, spbx, spbh,
                                                Wu, buv, Ws, bsv, Wp, bpv, out);
}